// Round 5
// baseline (28.339 us; speedup 1.0000x reference)
//
#include <hip/hip_runtime.h>
#include <math.h>

typedef _Float16 f16x8 __attribute__((ext_vector_type(8)));
typedef float    f32x4 __attribute__((ext_vector_type(4)));

#define SCRW 132
#define MLDW 33

typedef __attribute__((address_space(3))) void lds_void;
typedef const __attribute__((address_space(1))) void glb_void;

__device__ __forceinline__ f32x4 mfma16(f16x8 a, f16x8 b, f32x4 c) {
  return __builtin_amdgcn_mfma_f32_16x16x32_f16(a, b, c, 0, 0, 0);
}

__device__ __forceinline__ void pack8(const float* v, f16x8& hi, f16x8& lo) {
#pragma unroll
  for (int j = 0; j < 8; ++j) {
    _Float16 h = (_Float16)v[j];
    hi[j] = h;
    lo[j] = (_Float16)(v[j] - (float)h);
  }
}

__device__ __forceinline__ f16x8 bfrag8(const float* p) {
  const f32x4* q = (const f32x4*)p;
  f32x4 w0 = q[0], w1 = q[1];
  f16x8 b;
#pragma unroll
  for (int j = 0; j < 4; ++j) { b[j] = (_Float16)w0[j]; b[j + 4] = (_Float16)w1[j]; }
  return b;
}

__device__ __forceinline__ void splitP(const float* p, f16x8& hi, f16x8& lo) {
  const f32x4* q = (const f32x4*)p;
  f32x4 a0 = q[0], a1 = q[1];
#pragma unroll
  for (int j = 0; j < 4; ++j) {
    _Float16 h0 = (_Float16)a0[j], h1 = (_Float16)a1[j];
    hi[j] = h0; hi[j + 4] = h1;
    lo[j]     = (_Float16)(a0[j] - (float)h0);
    lo[j + 4] = (_Float16)(a1[j] - (float)h1);
  }
}

// stream one 2-image chunk (6272 B) global -> LDS, coalesced (7 VMEM ops)
__device__ __forceinline__ void load_chunk2(const float* gsrc, float* lbase, int l) {
#pragma unroll
  for (int i = 0; i < 6; ++i)
    __builtin_amdgcn_global_load_lds((glb_void*)(gsrc + i * 256 + l * 4),
                                     (lds_void*)(lbase + i * 256), 16, 0, 0);
  if (l < 8)
    __builtin_amdgcn_global_load_lds((glb_void*)(gsrc + 1536 + l * 4),
                                     (lds_void*)(lbase + 1536), 16, 0, 0);
}

// 8 samples / wave (MFMA columns 0-7 real, 8-15 inert). 2048 waves = 2/SIMD.
__global__ __launch_bounds__(256, 2) void mnist_fused(
    const float* __restrict__ img,  const float* __restrict__ Wff,
    const float* __restrict__ Wfb,  const float* __restrict__ Wvel,
    const float* __restrict__ Wc1,  const float* __restrict__ bc1,
    const float* __restrict__ Wc2,  const float* __restrict__ bc2,
    float* __restrict__ out) {
  __shared__ float img_lds[4][2][1568];     // 49 KB: per-wave 2-image ping-pong
  __shared__ float scr_all[4][1104];        // 17 KB: per-wave scratch (M / features)

  const int tid = threadIdx.x;
  const int wv = tid >> 6, l = tid & 63;
  const int g = l >> 4, c = l & 15;
  float* scr  = scr_all[wv];
  float* Mlds = scr;
  float* buf0 = &img_lds[wv][0][0];
  float* buf1 = &img_lds[wv][1][0];
  const int s0 = (blockIdx.x * 4 + wv) * 8;
  const f32x4 zero = {0.f, 0.f, 0.f, 0.f};

  // ---- weight loads FIRST (retire before chunks -> counted chunk waits stay exact) ----
  f32x4 rff[4], rfb[4];
  rff[0] = *(const f32x4*)(Wff + c * 32 + g * 8);
  rff[1] = *(const f32x4*)(Wff + c * 32 + g * 8 + 4);
  rff[2] = *(const f32x4*)(Wff + (16 + c) * 32 + g * 8);
  rff[3] = *(const f32x4*)(Wff + (16 + c) * 32 + g * 8 + 4);
  rfb[0] = *(const f32x4*)(Wfb + c * 32 + g * 8);
  rfb[1] = *(const f32x4*)(Wfb + c * 32 + g * 8 + 4);
  rfb[2] = *(const f32x4*)(Wfb + (16 + c) * 32 + g * 8);
  rfb[3] = *(const f32x4*)(Wfb + (16 + c) * 32 + g * 8 + 4);
  float rT0[8], rT1[8];
#pragma unroll
  for (int j = 0; j < 8; ++j) {
    rT0[j] = Wfb[(g * 8 + j) * 32 + c];
    rT1[j] = Wfb[(g * 8 + j) * 32 + 16 + c];
  }
  float2 wv0[4], wv1[4];
#pragma unroll
  for (int e = 0; e < 4; ++e) {
    wv0[e] = ((const float2*)Wvel)[g * 4 + e];
    wv1[e] = ((const float2*)Wvel)[16 + g * 4 + e];
  }
  __builtin_amdgcn_sched_barrier(0);

  // ---- issue chunks 0 and 1 (2-deep pipeline) ----
  load_chunk2(img + (size_t)(s0)     * 784, buf0, l);
  load_chunk2(img + (size_t)(s0 + 2) * 784, buf1, l);
  __builtin_amdgcn_sched_barrier(0);

  // ---- tap index math (overlaps DMA) ----
  int loB[8], taB[8], tbB[8], loQ[8];
  float wB[8], wQ[8];
#pragma unroll
  for (int j = 0; j < 8; ++j) {
    int u = g * 8 + j;
    float pos = 24.5f * (float)u + 11.75f;
    loB[j] = (int)pos; wB[j] = pos - (float)loB[j];
    int lt = loB[j];
    taB[j] = (lt % 28) * 28 + lt / 28;
    lt += 1;
    tbB[j] = (lt % 28) * 28 + lt / 28;
  }
#pragma unroll
  for (int e2 = 0; e2 < 8; ++e2) {
    int u = (e2 >> 2) * 16 + g * 4 + (e2 & 3);
    float pos = 24.5f * (float)u + 11.75f;
    loQ[e2] = (int)pos; wQ[e2] = pos - (float)loQ[e2];
  }

  // ---- weight fragments ----
  f16x8 bffh0, bffl0, bffh1, bffl1, bfbh0, bfbl0, bfbh1, bfbl1;
  {
    float t[8];
#pragma unroll
    for (int j = 0; j < 4; ++j) { t[j] = rff[0][j]; t[4 + j] = rff[1][j]; }
    pack8(t, bffh0, bffl0);
#pragma unroll
    for (int j = 0; j < 4; ++j) { t[j] = rff[2][j]; t[4 + j] = rff[3][j]; }
    pack8(t, bffh1, bffl1);
#pragma unroll
    for (int j = 0; j < 4; ++j) { t[j] = rfb[0][j]; t[4 + j] = rfb[1][j]; }
    pack8(t, bfbh0, bfbl0);
#pragma unroll
    for (int j = 0; j < 4; ++j) { t[j] = rfb[2][j]; t[4 + j] = rfb[3][j]; }
    pack8(t, bfbh1, bfbl1);
  }
  f16x8 aT0h, aT0l, aT1h, aT1l;
  pack8(rT0, aT0h, aT0l);
  pack8(rT1, aT1h, aT1l);

  // ---- M = Wfb^T @ Wff^T -> LDS -> A-frags of -M^T ----
  f32x4 m00 = mfma16(aT0h, bffl0, mfma16(aT0l, bffh0, mfma16(aT0h, bffh0, zero)));
  f32x4 m01 = mfma16(aT0h, bffl1, mfma16(aT0l, bffh1, mfma16(aT0h, bffh1, zero)));
  f32x4 m10 = mfma16(aT1h, bffl0, mfma16(aT1l, bffh0, mfma16(aT1h, bffh0, zero)));
  f32x4 m11 = mfma16(aT1h, bffl1, mfma16(aT1l, bffh1, mfma16(aT1h, bffh1, zero)));
#pragma unroll
  for (int r = 0; r < 4; ++r) {
    Mlds[(g * 4 + r) * MLDW + c]            = m00[r];
    Mlds[(g * 4 + r) * MLDW + 16 + c]       = m01[r];
    Mlds[(16 + g * 4 + r) * MLDW + c]       = m10[r];
    Mlds[(16 + g * 4 + r) * MLDW + 16 + c]  = m11[r];
  }
  f16x8 nMt0h, nMt0l, nMt1h, nMt1l;
  {
    float m[8];
#pragma unroll
    for (int j = 0; j < 8; ++j) m[j] = -Mlds[(g * 8 + j) * MLDW + c];
    pack8(m, nMt0h, nMt0l);
#pragma unroll
    for (int j = 0; j < 8; ++j) m[j] = -Mlds[(g * 8 + j) * MLDW + 16 + c];
    pack8(m, nMt1h, nMt1l);
  }
  __builtin_amdgcn_sched_barrier(0);

  // ---- chunk pipeline: wait(counted) -> extract -> reissue ----
  float sB[8] = {}, tB[8] = {}, sQ[8] = {};

#define EXTRACT(CH, BUF)                                                     \
  if ((c >> 1) == (CH)) {                                                    \
    const float* base = (BUF) + (c & 1) * 784;                               \
    _Pragma("unroll") for (int j = 0; j < 8; ++j) {                          \
      float a = base[loB[j]], b2 = base[loB[j] + 1];                         \
      sB[j] = (a + (b2 - a) * wB[j]) * 80.0f;                                \
    }                                                                        \
    _Pragma("unroll") for (int j = 0; j < 8; ++j) {                          \
      float a = base[taB[j]], b2 = base[tbB[j]];                             \
      tB[j] = (a + (b2 - a) * wB[j]) * 40.0f;                                \
    }                                                                        \
    _Pragma("unroll") for (int e2 = 0; e2 < 8; ++e2) {                       \
      float a = base[loQ[e2]], b2 = base[loQ[e2] + 1];                       \
      sQ[e2] = (a + (b2 - a) * wQ[e2]) * 80.0f;                              \
    }                                                                        \
  }

  asm volatile("s_waitcnt vmcnt(7)" ::: "memory");   // chunk0 done, chunk1 flying
  __builtin_amdgcn_sched_barrier(0);
  EXTRACT(0, buf0)
  asm volatile("s_waitcnt lgkmcnt(0)" ::: "memory");
  __builtin_amdgcn_sched_barrier(0);
  load_chunk2(img + (size_t)(s0 + 4) * 784, buf0, l);   // chunk2
  __builtin_amdgcn_sched_barrier(0);

  asm volatile("s_waitcnt vmcnt(7)" ::: "memory");   // chunk1 done, chunk2 flying
  __builtin_amdgcn_sched_barrier(0);
  EXTRACT(1, buf1)
  asm volatile("s_waitcnt lgkmcnt(0)" ::: "memory");
  __builtin_amdgcn_sched_barrier(0);
  load_chunk2(img + (size_t)(s0 + 6) * 784, buf1, l);   // chunk3
  __builtin_amdgcn_sched_barrier(0);

  asm volatile("s_waitcnt vmcnt(7)" ::: "memory");   // chunk2 done, chunk3 flying
  __builtin_amdgcn_sched_barrier(0);
  EXTRACT(2, buf0)

  asm volatile("s_waitcnt vmcnt(0)" ::: "memory");   // chunk3 done
  __builtin_amdgcn_sched_barrier(0);
  EXTRACT(3, buf1)
#undef EXTRACT

  // ---- B-frags of Sens^T / Td^T; sens quads ----
  f16x8 snh, snl, tdh, tdl;
  pack8(sB, snh, snl);
  pack8(tB, tdh, tdl);
  f32x4 SN0 = {sQ[0], sQ[1], sQ[2], sQ[3]};
  f32x4 SN1 = {sQ[4], sQ[5], sQ[6], sQ[7]};

  // ---- SF = Wff·Sens^T ; YFB = relu(Wfb·Td^T) ----
  f32x4 SF0 = mfma16(bffh0, snh, zero);
  SF0 += mfma16(bffl0, snh, mfma16(bffh0, snl, zero));
  f32x4 SF1 = mfma16(bffh1, snh, zero);
  SF1 += mfma16(bffl1, snh, mfma16(bffh1, snl, zero));
  f32x4 YFB0 = mfma16(bfbh0, tdh, zero);
  YFB0 += mfma16(bfbl0, tdh, mfma16(bfbh0, tdl, zero));
  f32x4 YFB1 = mfma16(bfbh1, tdh, zero);
  YFB1 += mfma16(bfbl1, tdh, mfma16(bfbh1, tdl, zero));
#pragma unroll
  for (int e = 0; e < 4; ++e) {
    YFB0[e] = fmaxf(YFB0[e], 0.f);
    YFB1[e] = fmaxf(YFB1[e], 0.f);
  }

  // ---- register recurrence (bpermute C-quads -> B-frags) ----
  const int addrA = ((2 * (g & 1)) * 16 + c) * 4;
  const int addrB = addrA + 64;
  const bool hiG = (g >= 2);
  f32x4 r6q0 = zero, r6q1 = zero;
  f32x4 yf0 = zero, yf1 = zero, dq0 = zero, dq1 = zero;
  const float VX[3] = {0.2f, 0.0f, 0.15f};
  const float VY[3] = {0.0f, 0.2f, 0.15f};
#pragma unroll
  for (int v = 0; v < 3; ++v) {
    f32x4 vq0, vq1;
#pragma unroll
    for (int e = 0; e < 4; ++e) {
      vq0[e] = wv0[e].x * VX[v] + wv0[e].y * VY[v];
      vq1[e] = wv1[e].x * VX[v] + wv1[e].y * VY[v];
    }
#pragma unroll
    for (int st = 0; st < 3; ++st) {
      float t[8];
#pragma unroll
      for (int e = 0; e < 4; ++e) {
        int q0i = __float_as_int(r6q0[e]), q1i = __float_as_int(r6q1[e]);
        float a0 = __int_as_float(__builtin_amdgcn_ds_bpermute(addrA, q0i));
        float a1 = __int_as_float(__builtin_amdgcn_ds_bpermute(addrA, q1i));
        float b0 = __int_as_float(__builtin_amdgcn_ds_bpermute(addrB, q0i));
        float b1 = __int_as_float(__builtin_amdgcn_ds_bpermute(addrB, q1i));
        t[e]     = hiG ? a1 : a0;
        t[4 + e] = hiG ? b1 : b0;
      }
      f16x8 bh, bl;
      pack8(t, bh, bl);
      f32x4 y0 = mfma16(nMt0h, bh, SF0);
      y0 += mfma16(nMt0l, bh, mfma16(nMt0h, bl, zero));
      f32x4 y1 = mfma16(nMt1h, bh, SF1);
      y1 += mfma16(nMt1l, bh, mfma16(nMt1h, bl, zero));
      if (v == 2 && st == 2) {
        f32x4 p0 = mfma16(bfbh0, bh, zero);
        p0 += mfma16(bfbl0, bh, mfma16(bfbh0, bl, zero));
        f32x4 p1 = mfma16(bfbh1, bh, zero);
        p1 += mfma16(bfbl1, bh, mfma16(bfbh1, bl, zero));
#pragma unroll
        for (int e = 0; e < 4; ++e) { dq0[e] = SN0[e] - p0[e]; dq1[e] = SN1[e] - p1[e]; }
      }
#pragma unroll
      for (int e = 0; e < 4; ++e) {
        yf0[e] = fmaxf(y0[e], 0.f);
        yf1[e] = fmaxf(y1[e], 0.f);
        r6q0[e] += 0.1f * (yf0[e] - r6q0[e] + YFB0[e] + vq0[e]);
        r6q1[e] += 0.1f * (yf1[e] - r6q1[e] + YFB1[e] + vq1[e]);
      }
    }
  }

  // ---- feature rows (samples 0-7 only) ----
  if (c < 8) {
    const int b0 = c * SCRW;
#pragma unroll
    for (int e = 0; e < 4; ++e) {
      scr[b0 +       g * 4 + e] = yf0[e];
      scr[b0 + 16  + g * 4 + e] = yf1[e];
      scr[b0 + 32  + g * 4 + e] = YFB0[e];
      scr[b0 + 48  + g * 4 + e] = YFB1[e];
      scr[b0 + 64  + g * 4 + e] = r6q0[e];
      scr[b0 + 80  + g * 4 + e] = r6q1[e];
      scr[b0 + 96  + g * 4 + e] = fabsf(dq0[e]);
      scr[b0 + 112 + g * 4 + e] = fabsf(dq1[e]);
    }
  }

  // ---- classifier ----
  f32x4 acc0 = zero, acc1 = zero, acc2 = zero, acc3 = zero;
#pragma unroll
  for (int kb = 0; kb < 4; ++kb) {
    f16x8 fhi, flo;
    splitP(scr + (c & 7) * SCRW + kb * 32 + g * 8, fhi, flo);
    const int ko = kb * 32 + g * 8;
    f16x8 b0 = bfrag8(Wc1 + (size_t)(c)      * 128 + ko);
    f16x8 b1 = bfrag8(Wc1 + (size_t)(16 + c) * 128 + ko);
    f16x8 b2 = bfrag8(Wc1 + (size_t)(32 + c) * 128 + ko);
    f16x8 b3 = bfrag8(Wc1 + (size_t)(48 + c) * 128 + ko);
    acc0 = mfma16(flo, b0, mfma16(fhi, b0, acc0));
    acc1 = mfma16(flo, b1, mfma16(fhi, b1, acc1));
    acc2 = mfma16(flo, b2, mfma16(fhi, b2, acc2));
    acc3 = mfma16(flo, b3, mfma16(fhi, b3, acc3));
  }
  float h[4][4];
  const float B0 = bc1[c], B1 = bc1[16 + c], B2 = bc1[32 + c], B3 = bc1[48 + c];
#pragma unroll
  for (int r = 0; r < 4; ++r) {
    float x0 = acc0[r] + B0, x1 = acc1[r] + B1, x2 = acc2[r] + B2, x3 = acc3[r] + B3;
    h[r][0] = 0.5f * x0 * (1.0f + erff(x0 * 0.70710678118654752f));
    h[r][1] = 0.5f * x1 * (1.0f + erff(x1 * 0.70710678118654752f));
    h[r][2] = 0.5f * x2 * (1.0f + erff(x2 * 0.70710678118654752f));
    h[r][3] = 0.5f * x3 * (1.0f + erff(x3 * 0.70710678118654752f));
  }
  if (g < 2) {
#pragma unroll
    for (int r = 0; r < 4; ++r) {
      int row = (g * 4 + r) * SCRW;
#pragma unroll
      for (int nb = 0; nb < 4; ++nb) scr[row + nb * 16 + c] = h[r][nb];
    }
  }
  f32x4 accL = zero;
#pragma unroll
  for (int kb = 0; kb < 2; ++kb) {
    f16x8 hhi, hlo;
    splitP(scr + (c & 7) * SCRW + kb * 32 + g * 8, hhi, hlo);
    f16x8 b;
    if (c < 10) {
      b = bfrag8(Wc2 + (size_t)c * 64 + kb * 32 + g * 8);
    } else {
#pragma unroll
      for (int j = 0; j < 8; ++j) b[j] = (_Float16)0.f;
    }
    accL = mfma16(hlo, b, mfma16(hhi, b, accL));
  }
  if (c < 10 && g < 2) {
    const float bb = bc2[c];
#pragma unroll
    for (int r = 0; r < 4; ++r)
      out[(size_t)(s0 + g * 4 + r) * 10 + c] = accL[r] + bb;
  }
}

extern "C" void kernel_launch(void* const* d_in, const int* in_sizes, int n_in,
                              void* d_out, int out_size, void* d_ws, size_t ws_size,
                              hipStream_t stream) {
  const float* img  = (const float*)d_in[0];
  const float* Wff  = (const float*)d_in[1];
  const float* Wfb  = (const float*)d_in[2];
  const float* Wvel = (const float*)d_in[3];
  const float* Wc1  = (const float*)d_in[4];
  const float* bc1  = (const float*)d_in[5];
  const float* Wc2  = (const float*)d_in[6];
  const float* bc2  = (const float*)d_in[7];
  float* out = (float*)d_out;
  const int B = in_sizes[0] / 784;     // 16384
  const int grid = B / 32;             // 512 blocks: 4 waves x 8 samples
  hipLaunchKernelGGL(mnist_fused, dim3(grid), dim3(256), 0, stream,
                     img, Wff, Wfb, Wvel, Wc1, bc1, Wc2, bc2, out);
}